// Round 2
// baseline (616.584 us; speedup 1.0000x reference)
//
#include <hip/hip_runtime.h>
#include <hip/hip_bf16.h>

typedef __attribute__((ext_vector_type(4))) float floatx4;
typedef __bf16 bf16x8 __attribute__((ext_vector_type(8)));

static __device__ __forceinline__ unsigned short f2bf(float x) {
    union { float f; unsigned int u; } v; v.f = x;
    unsigned int u = v.u;
    unsigned int r = u + 0x7FFF + ((u >> 16) & 1);   // round-to-nearest-even
    return (unsigned short)(r >> 16);
}

static __device__ __forceinline__ __bf16 tobf(float f) {
    __hip_bfloat16 h = __float2bfloat16(f);
    __bf16 r;
    __builtin_memcpy(&r, &h, 2);
    return r;
}

// Kernel 1 (unchanged from round 1 — control): per-node transform. 2 nodes/block.
//   support[k] = sum_j in[j] * W[n][j][k]
//   h[j]      = sum_k R[n][j][k] * support[k]
// Writes h transposed as bf16: h_t[feature j][node n]
__global__ __launch_bounds__(256) void node_transform(
    const float* __restrict__ input,      // [4096][128]
    const float* __restrict__ rel,        // [4096][128][128]
    const float* __restrict__ wts,        // [4096][128][128]
    unsigned int* __restrict__ h_t)       // [128][2048] uint = [128][4096] bf16
{
    __shared__ float s_in[2][128];
    __shared__ float s_part[2][4][128];
    __shared__ float s_sup[2][128];
    __shared__ float s_h[2][128];

    const int tid = threadIdx.x;
    const int b = blockIdx.x;

    if (tid < 64) {
        float4 v = ((const float4*)input)[b * 64 + tid];
        ((float4*)&s_in[0][0])[tid] = v;
    }
    __syncthreads();

    const int node = tid >> 7;
    const int tl   = tid & 127;
    const int n    = b * 2 + node;

    // ---- stage 1: support = in^T * W ----
    {
        const int jg = tl >> 5;
        const int kq = tl & 31;
        const float4* W4 = (const float4*)(wts + (size_t)n * 16384);
        float4 acc = {0.f, 0.f, 0.f, 0.f};
        const int j0 = jg * 32;
        #pragma unroll 8
        for (int jj = 0; jj < 32; ++jj) {
            const int j = j0 + jj;
            const float x = s_in[node][j];
            const float4 w = W4[j * 32 + kq];
            acc.x += x * w.x; acc.y += x * w.y;
            acc.z += x * w.z; acc.w += x * w.w;
        }
        ((float4*)&s_part[node][jg][0])[kq] = acc;
    }
    __syncthreads();
    s_sup[node][tl] = s_part[node][0][tl] + s_part[node][1][tl]
                    + s_part[node][2][tl] + s_part[node][3][tl];
    __syncthreads();

    // ---- stage 2: h = R * support ----
    {
        const int wnode = tl >> 6;
        const int lane  = tl & 63;
        const int half  = lane >> 5;
        const int l     = lane & 31;
        const float4* R4 = (const float4*)(rel + (size_t)n * 16384);
        const float4 sv = ((const float4*)&s_sup[node][0])[l];
        #pragma unroll 4
        for (int it = 0; it < 32; ++it) {
            const int j = wnode * 64 + it * 2 + half;
            const float4 r = R4[j * 32 + l];
            float p = r.x * sv.x + r.y * sv.y + r.z * sv.z + r.w * sv.w;
            p += __shfl_xor(p, 1);
            p += __shfl_xor(p, 2);
            p += __shfl_xor(p, 4);
            p += __shfl_xor(p, 8);
            p += __shfl_xor(p, 16);
            if (l == 0) s_h[node][j] = p;
        }
    }
    __syncthreads();

    if (tid < 128) {
        const unsigned int lo = f2bf(s_h[0][tid]);
        const unsigned int hi = f2bf(s_h[1][tid]);
        h_t[tid * 2048 + b] = lo | (hi << 16);
    }
}

// Kernel 2: out = adj @ h + bias, bf16 MFMA — barrier-free, LDS-free.
// Block: 512 threads = 8 waves; block covers 16 rows x 128 cols; each wave one
// 16x16 output tile (cols wave*16..+16). Fragments loaded straight from global:
//   A-frag: adj[m0+ (lane&15)][kb + (lane>>4)*8 ..+8]   (k-contiguous fp32->bf16)
//   B-frag: ht[wave*16+(lane&15)][kb + (lane>>4)*8 ..+8] (k-contiguous bf16, L2-hit)
// All 8 waves read the SAME A rows -> L1/L2 hits after first toucher. No
// __syncthreads in the K-loop: waves free-run, unroll-4 keeps 8 loads in flight.
__global__ __launch_bounds__(512) void agg_gemm(
    const float* __restrict__ A,              // [4096][4096] fp32 adjacency
    const unsigned short* __restrict__ ht,    // [128][4096] bf16 (h transposed)
    const float* __restrict__ bias,           // [128]
    float* __restrict__ out)                  // [4096][128] fp32
{
    const int tid  = threadIdx.x;
    const int wave = tid >> 6;                // 0..7 -> col group
    const int lane = tid & 63;
    const int m0   = blockIdx.x * 16;
    const int mn   = lane & 15;               // A row m / B col n
    const int kq   = lane >> 4;               // k-quad: 8 contiguous k per lane

    const float*          arow = A  + (size_t)(m0 + mn) * 4096 + kq * 8;
    const unsigned short* brow = ht + (size_t)(wave * 16 + mn) * 4096 + kq * 8;

    floatx4 acc = {0.f, 0.f, 0.f, 0.f};

    #pragma unroll 4
    for (int kb = 0; kb < 4096; kb += 32) {
        const float4 a0 = *(const float4*)(arow + kb);
        const float4 a1 = *(const float4*)(arow + kb + 4);
        const bf16x8 bfr = *(const bf16x8*)(brow + kb);
        bf16x8 af;
        af[0] = tobf(a0.x); af[1] = tobf(a0.y);
        af[2] = tobf(a0.z); af[3] = tobf(a0.w);
        af[4] = tobf(a1.x); af[5] = tobf(a1.y);
        af[6] = tobf(a1.z); af[7] = tobf(a1.w);
        acc = __builtin_amdgcn_mfma_f32_16x16x32_bf16(af, bfr, acc, 0, 0, 0);
    }

    // epilogue: C/D layout col=lane&15, row=(lane>>4)*4+reg
    const int col = wave * 16 + mn;
    const int r0  = kq * 4;
    const float bv = bias[col];
    #pragma unroll
    for (int r = 0; r < 4; ++r) {
        out[(size_t)(m0 + r0 + r) * 128 + col] = acc[r] + bv;
    }
}

extern "C" void kernel_launch(void* const* d_in, const int* in_sizes, int n_in,
                              void* d_out, int out_size, void* d_ws, size_t ws_size,
                              hipStream_t stream) {
    const float* input = (const float*)d_in[0];   // [4096][128]
    const float* adj   = (const float*)d_in[1];   // [4096][4096]
    const float* rel   = (const float*)d_in[2];   // [4096][128][128]
    const float* wts   = (const float*)d_in[3];   // [4096][128][128]
    const float* bias  = (const float*)d_in[4];   // [128]
    float* out = (float*)d_out;

    unsigned int* h_t = (unsigned int*)d_ws;      // 1 MB bf16 h, transposed [128][4096]

    node_transform<<<2048, 256, 0, stream>>>(input, rel, wts, h_t);
    agg_gemm<<<256, 512, 0, stream>>>(adj, (const unsigned short*)d_ws, bias, out);
}

// Round 3
// 562.288 us; speedup vs baseline: 1.0966x; 1.0966x over previous
//
#include <hip/hip_runtime.h>
#include <hip/hip_bf16.h>

typedef __attribute__((ext_vector_type(4))) float floatx4;
typedef __bf16 bf16x8 __attribute__((ext_vector_type(8)));

static __device__ __forceinline__ unsigned short f2bf(float x) {
    union { float f; unsigned int u; } v; v.f = x;
    unsigned int u = v.u;
    unsigned int r = u + 0x7FFF + ((u >> 16) & 1);   // round-to-nearest-even
    return (unsigned short)(r >> 16);
}

// Kernel 1 (unchanged — control): per-node transform. 2 nodes/block.
//   support[k] = sum_j in[j] * W[n][j][k]
//   h[j]      = sum_k R[n][j][k] * support[k]
// Writes h transposed as bf16: h_t[feature j][node n]
__global__ __launch_bounds__(256) void node_transform(
    const float* __restrict__ input,      // [4096][128]
    const float* __restrict__ rel,        // [4096][128][128]
    const float* __restrict__ wts,        // [4096][128][128]
    unsigned int* __restrict__ h_t)       // [128][2048] uint = [128][4096] bf16
{
    __shared__ float s_in[2][128];
    __shared__ float s_part[2][4][128];
    __shared__ float s_sup[2][128];
    __shared__ float s_h[2][128];

    const int tid = threadIdx.x;
    const int b = blockIdx.x;

    if (tid < 64) {
        float4 v = ((const float4*)input)[b * 64 + tid];
        ((float4*)&s_in[0][0])[tid] = v;
    }
    __syncthreads();

    const int node = tid >> 7;
    const int tl   = tid & 127;
    const int n    = b * 2 + node;

    // ---- stage 1: support = in^T * W ----
    {
        const int jg = tl >> 5;
        const int kq = tl & 31;
        const float4* W4 = (const float4*)(wts + (size_t)n * 16384);
        float4 acc = {0.f, 0.f, 0.f, 0.f};
        const int j0 = jg * 32;
        #pragma unroll 8
        for (int jj = 0; jj < 32; ++jj) {
            const int j = j0 + jj;
            const float x = s_in[node][j];
            const float4 w = W4[j * 32 + kq];
            acc.x += x * w.x; acc.y += x * w.y;
            acc.z += x * w.z; acc.w += x * w.w;
        }
        ((float4*)&s_part[node][jg][0])[kq] = acc;
    }
    __syncthreads();
    s_sup[node][tl] = s_part[node][0][tl] + s_part[node][1][tl]
                    + s_part[node][2][tl] + s_part[node][3][tl];
    __syncthreads();

    // ---- stage 2: h = R * support ----
    {
        const int wnode = tl >> 6;
        const int lane  = tl & 63;
        const int half  = lane >> 5;
        const int l     = lane & 31;
        const float4* R4 = (const float4*)(rel + (size_t)n * 16384);
        const float4 sv = ((const float4*)&s_sup[node][0])[l];
        #pragma unroll 4
        for (int it = 0; it < 32; ++it) {
            const int j = wnode * 64 + it * 2 + half;
            const float4 r = R4[j * 32 + l];
            float p = r.x * sv.x + r.y * sv.y + r.z * sv.z + r.w * sv.w;
            p += __shfl_xor(p, 1);
            p += __shfl_xor(p, 2);
            p += __shfl_xor(p, 4);
            p += __shfl_xor(p, 8);
            p += __shfl_xor(p, 16);
            if (l == 0) s_h[node][j] = p;
        }
    }
    __syncthreads();

    if (tid < 128) {
        const unsigned int lo = f2bf(s_h[0][tid]);
        const unsigned int hi = f2bf(s_h[1][tid]);
        h_t[tid * 2048 + b] = lo | (hi << 16);
    }
}

// Kernel 2: partial[s] = adj[:, s*1024:(s+1)*1024] @ h[s*1024:(s+1)*1024, :]
// Split-K=4 LDS-staged bf16 MFMA. Grid 1024 = 256 row-tiles x 4 K-splits,
// 512 threads (8 waves, one 16x16 tile each). LDS 38.25 KB -> 4 blocks/CU,
// 32 waves/CU: barrier drains in one block overlap other blocks' compute.
__global__ __launch_bounds__(512) void agg_gemm_splitk(
    const float* __restrict__ A,              // [4096][4096] fp32 adjacency
    const unsigned short* __restrict__ ht,    // [128][4096] bf16 (h transposed)
    float* __restrict__ part)                 // [4][4096][128] fp32 partials
{
    __shared__ __align__(16) unsigned short As[16][136];
    __shared__ __align__(16) unsigned short Bs[128][136];

    const int tid  = threadIdx.x;
    const int wave = tid >> 6;                // 0..7 -> col group
    const int lane = tid & 63;
    const int s    = blockIdx.x & 3;          // K-split
    const int m0   = (blockIdx.x >> 2) * 16;  // row tile
    const int kbase = s * 1024;

    floatx4 acc = {0.f, 0.f, 0.f, 0.f};

    const int ar = tid >> 5;                  // A stage: row 0..15
    const int ac = (tid & 31) * 4;            //          col quad
    const int bj = tid >> 2;                  // B stage: feature row 0..127
    const int bs = tid & 3;                   //          16B sub-chunk

    for (int kb = kbase; kb < kbase + 1024; kb += 128) {
        __syncthreads();                      // protect LDS from previous iter reads
        // stage A tile: 16 x 128 fp32 -> bf16 (512 thr x 1 float4, coalesced)
        {
            const float4 v = *(const float4*)(A + (size_t)(m0 + ar) * 4096 + kb + ac);
            const unsigned int p0 = (unsigned int)f2bf(v.x) | ((unsigned int)f2bf(v.y) << 16);
            const unsigned int p1 = (unsigned int)f2bf(v.z) | ((unsigned int)f2bf(v.w) << 16);
            *(uint2*)&As[ar][ac] = make_uint2(p0, p1);
        }
        // stage B tile: 128 x 128 bf16 (512 thr x 4 uint4)
        {
            const unsigned short* src = ht + (size_t)bj * 4096 + kb + bs * 8;
            #pragma unroll
            for (int i = 0; i < 4; ++i) {
                const uint4 v = *(const uint4*)(src + i * 32);
                *(uint4*)&Bs[bj][bs * 8 + i * 32] = v;
            }
        }
        __syncthreads();
        // compute: wave covers cols [wave*16, wave*16+16)
        const int mn = lane & 15;             // A row m / B col n
        const int kq = lane >> 4;             // k-quad: 8 contiguous k per lane
        const unsigned short* arow = &As[mn][kq * 8];
        const unsigned short* brow = &Bs[wave * 16 + mn][kq * 8];
        #pragma unroll
        for (int k0 = 0; k0 < 128; k0 += 32) {
            const bf16x8 af  = *(const bf16x8*)(arow + k0);
            const bf16x8 bfr = *(const bf16x8*)(brow + k0);
            acc = __builtin_amdgcn_mfma_f32_16x16x32_bf16(af, bfr, acc, 0, 0, 0);
        }
    }

    // epilogue: C/D layout col=lane&15, row=(lane>>4)*4+reg
    const int col = wave * 16 + (lane & 15);
    const int r0  = (lane >> 4) * 4;
    float* dst = part + ((size_t)s * 4096 + m0 + r0) * 128 + col;
    #pragma unroll
    for (int r = 0; r < 4; ++r) {
        dst[(size_t)r * 128] = acc[r];
    }
}

// Kernel 3: out = sum_s part[s] + bias. 131072 float4s, 1 per thread.
__global__ __launch_bounds__(256) void reduce_bias(
    const float* __restrict__ part,           // [4][4096][128]
    const float* __restrict__ bias,           // [128]
    float* __restrict__ out)                  // [4096][128]
{
    const int f = blockIdx.x * 256 + threadIdx.x;   // float4 index, 0..131071
    const float4* p4 = (const float4*)part;
    const float4 b = ((const float4*)bias)[f & 31];
    float4 s0 = p4[f];
    float4 s1 = p4[131072 + f];
    float4 s2 = p4[262144 + f];
    float4 s3 = p4[393216 + f];
    float4 r;
    r.x = s0.x + s1.x + s2.x + s3.x + b.x;
    r.y = s0.y + s1.y + s2.y + s3.y + b.y;
    r.z = s0.z + s1.z + s2.z + s3.z + b.z;
    r.w = s0.w + s1.w + s2.w + s3.w + b.w;
    ((float4*)out)[f] = r;
}

extern "C" void kernel_launch(void* const* d_in, const int* in_sizes, int n_in,
                              void* d_out, int out_size, void* d_ws, size_t ws_size,
                              hipStream_t stream) {
    const float* input = (const float*)d_in[0];   // [4096][128]
    const float* adj   = (const float*)d_in[1];   // [4096][4096]
    const float* rel   = (const float*)d_in[2];   // [4096][128][128]
    const float* wts   = (const float*)d_in[3];   // [4096][128][128]
    const float* bias  = (const float*)d_in[4];   // [128]
    float* out = (float*)d_out;

    unsigned int* h_t = (unsigned int*)d_ws;              // 1 MB: bf16 h transposed [128][4096]
    float* part = (float*)((char*)d_ws + (1 << 20));      // 8 MB: fp32 partials [4][4096][128]

    node_transform<<<2048, 256, 0, stream>>>(input, rel, wts, h_t);
    agg_gemm_splitk<<<1024, 512, 0, stream>>>(adj, (const unsigned short*)d_ws, part);
    reduce_bias<<<512, 256, 0, stream>>>(part, bias, out);
}